// Round 11
// baseline (720.312 us; speedup 1.0000x reference)
//
#include <hip/hip_runtime.h>

typedef __attribute__((ext_vector_type(8))) short bf16x8;
typedef __attribute__((ext_vector_type(4))) float f32x4;

#define NEG_SLOPE 0.2f

__device__ __forceinline__ unsigned short f2bf(float f){
  unsigned u = __float_as_uint(f);
  u = (u + 0x7fffu + ((u >> 16) & 1u)) >> 16;   // RNE
  return (unsigned short)u;
}
__device__ __forceinline__ float bflo(unsigned u){ return __uint_as_float(u << 16); }
__device__ __forceinline__ float bfhi(unsigned u){ return __uint_as_float(u & 0xffff0000u); }
__device__ __forceinline__ float lrelu(float x){ return x > 0.f ? x : NEG_SLOPE * x; }

// ---------------------------------------------------------------------------
// K0: [typehist | bprep].
// ---------------------------------------------------------------------------
__global__ __launch_bounds__(256) void k_prep(
    const int* __restrict__ vtype, int N, int* __restrict__ tcnt, int nbHN,
    const float* __restrict__ W, short* __restrict__ Bfrag){
  __shared__ int lcnt[4];
  int b = (int)blockIdx.x;
  if (b < nbHN){
    if (threadIdx.x < 4) lcnt[threadIdx.x] = 0;
    __syncthreads();
    int i = b * 256 + threadIdx.x;
    if (i < N) atomicAdd(&lcnt[vtype[i]], 1);
    __syncthreads();
    if (threadIdx.x < 4 && lcnt[threadIdx.x] > 0)
      atomicAdd(tcnt + threadIdx.x, lcnt[threadIdx.x]);
    return;
  }
  b -= nbHN;
  int u = b * 256 + threadIdx.x;                   // 0..65535
  int j = u & 7, lane = (u >> 3) & 63, ct = (u >> 9) & 31, ks = u >> 14;
  int k = ks * 32 + ((lane >> 4) << 3) + j;
  int col = (ct << 4) + (lane & 15);
  int t = col >> 7, o = col & 127;
  Bfrag[u] = (short)f2bf(W[(t * 128 + k) * 128 + o]);
}

// ---------------------------------------------------------------------------
// node placement; padded bucket bases derived inline from tcnt.
// ---------------------------------------------------------------------------
__global__ __launch_bounds__(256) void k_nodeplace(
    const int* __restrict__ vtype, int N, const int* __restrict__ tcnt,
    int* __restrict__ tcur, int* __restrict__ nsorted){
  __shared__ int lcnt[4];
  __shared__ int gbase[4];
  __shared__ int spb[4];
  int t = threadIdx.x;
  if (t < 4) lcnt[t] = 0;
  if (t == 0){
    int run = 0;
    #pragma unroll
    for (int k = 0; k < 4; ++k){ spb[k] = run; run += ((tcnt[k] + 63) >> 6) << 6; }
  }
  __syncthreads();
  int i = (int)blockIdx.x * 256 + t;
  int tt = 0, rank = 0;
  bool valid = i < N;
  if (valid){ tt = vtype[i]; rank = atomicAdd(&lcnt[tt], 1); }
  __syncthreads();
  if (t < 4 && lcnt[t] > 0) gbase[t] = atomicAdd(tcur + t, lcnt[t]);
  __syncthreads();
  if (valid) nsorted[spb[tt] + gbase[tt] + rank] = i;
}

// ---------------------------------------------------------------------------
// K_A v2: [histE x16 | histV x16 | gemm], block-index partition (hist first —
// they are the long pole; gemm fills remaining CUs).
// R11: ZERO-GLOBAL-ATOMIC histogram.  R5-R10 established the global-RMW
// phase is throughput-capped at ~22G/s (74us) regardless of ILP/splitting.
// Instead: each hist block owns a 1/16 key-range slice (LDS counters, fits
// the gemm's 32KB shB), streams the ENTIRE int key array (3.2MB, int4 loads,
// L2-resident — blocks scan in near-lockstep), ranks via LDS atomicAdd, and
// writes its cnt slice with plain stores.  Ranks stay dense-per-key/unique
// -> all downstream kernels byte-identical to R10.
// ---------------------------------------------------------------------------
#define NB_H 16                                    // blocks per key space

__global__ __launch_bounds__(256, 3) void k_gemm_hist(const float* __restrict__ X,
    const short* __restrict__ Bfrag, const int* __restrict__ nsorted,
    const int* __restrict__ tcnt, unsigned short* __restrict__ X0,
    const int* __restrict__ edges, const int* __restrict__ vertex, int NNZ,
    int* __restrict__ cnt, int E, int N,
    int* __restrict__ rank_e, int* __restrict__ rank_v){
  __shared__ short shB[8 * 4 * 64 * 8];            // 32KB: gemm slab / hist counters
  const int tid = threadIdx.x;
  const int b = (int)blockIdx.x;

  if (b < 2 * NB_H){                               // hist roles
    const int isV = (b >= NB_H) ? 1 : 0;
    const int bb = isV ? (b - NB_H) : b;
    const int K = isV ? N : E;                     // key-space size
    const int R = (K + NB_H - 1) / NB_H;           // owned range width
    const int lo = bb * R;
    const int hi = (lo + R < K) ? (lo + R) : K;
    const int* __restrict__ keys = isV ? vertex : edges;
    int* __restrict__ rnk = isV ? rank_v : rank_e;
    int* __restrict__ cp  = cnt + (isV ? E : 0);
    int* h = (int*)shB;                            // R ints (<= 6250 = 25KB)
    for (int k = tid; k < R; k += 256) h[k] = 0;
    __syncthreads();
    const int4* k4 = (const int4*)keys;
    int nv = NNZ >> 2;
    for (int j = tid; j < nv; j += 256){
      int4 kk = k4[j];
      int i = j << 2;
      if (kk.x >= lo && kk.x < hi) rnk[i]     = atomicAdd(&h[kk.x - lo], 1);
      if (kk.y >= lo && kk.y < hi) rnk[i + 1] = atomicAdd(&h[kk.y - lo], 1);
      if (kk.z >= lo && kk.z < hi) rnk[i + 2] = atomicAdd(&h[kk.z - lo], 1);
      if (kk.w >= lo && kk.w < hi) rnk[i + 3] = atomicAdd(&h[kk.w - lo], 1);
    }
    for (int i = (nv << 2) + tid; i < NNZ; i += 256){
      int kk = keys[i];
      if (kk >= lo && kk < hi) rnk[i] = atomicAdd(&h[kk - lo], 1);
    }
    __syncthreads();
    for (int k = tid; lo + k < hi; k += 256) cp[lo + k] = h[k];
    return;
  }

  const int q = b - 2 * NB_H;                      // gemm role
  const int rowIdx = q * 64;
  int pb1, pb2, pb3;
  {
    int run = ((tcnt[0] + 63) >> 6) << 6; pb1 = run;
    run    += ((tcnt[1] + 63) >> 6) << 6; pb2 = run;
    run    += ((tcnt[2] + 63) >> 6) << 6; pb3 = run;
  }
  const int t = (rowIdx >= pb1) + (rowIdx >= pb2) + (rowIdx >= pb3);

  // stage this type's full B (8 ct x 4 ks x 64 lanes, bf16x8 units)
  const bf16x8* Bv = (const bf16x8*)Bfrag;
  bf16x8* shBv = (bf16x8*)shB;
  #pragma unroll
  for (int v = 0; v < 8; ++v){
    int item = v * 256 + tid;                      // 0..2047
    int slab = item >> 6, ln = item & 63;          // slab = ks*8 + ctl
    int ks = slab >> 3, ctl = slab & 7;
    shBv[item] = Bv[((ks * 32 + 8 * t + ctl) * 64) + ln];
  }

  const int w = tid >> 6, lane = tid & 63;
  const int m = lane & 15, qq = lane >> 4;
  const int node = nsorted[rowIdx + w * 16 + m];   // -1 = pad sentinel

  bf16x8 afrag[4];
  #pragma unroll
  for (int ks = 0; ks < 4; ++ks){
    bf16x8 f;
    if (node >= 0){
      const float4* src = (const float4*)(X + (size_t)node * 128 + ks * 32 + qq * 8);
      float4 a = src[0], bq = src[1];
      f[0]=(short)f2bf(a.x); f[1]=(short)f2bf(a.y); f[2]=(short)f2bf(a.z); f[3]=(short)f2bf(a.w);
      f[4]=(short)f2bf(bq.x); f[5]=(short)f2bf(bq.y); f[6]=(short)f2bf(bq.z); f[7]=(short)f2bf(bq.w);
    } else {
      #pragma unroll
      for (int z = 0; z < 8; ++z) f[z] = 0;
    }
    afrag[ks] = f;
  }

  f32x4 acc[8];
  #pragma unroll
  for (int ct = 0; ct < 8; ++ct){
    acc[ct][0]=0.f; acc[ct][1]=0.f; acc[ct][2]=0.f; acc[ct][3]=0.f;
  }

  __syncthreads();
  #pragma unroll
  for (int ctl = 0; ctl < 8; ++ctl){
    #pragma unroll
    for (int ks = 0; ks < 4; ++ks){
      bf16x8 bf = shBv[(ks * 8 + ctl) * 64 + lane];
      acc[ctl] = __builtin_amdgcn_mfma_f32_16x16x32_bf16(afrag[ks], bf, acc[ctl], 0, 0, 0);
    }
  }

  const int col0 = lane & 15;
  #pragma unroll
  for (int rr = 0; rr < 4; ++rr){
    int row = nsorted[rowIdx + w * 16 + qq * 4 + rr];
    if (row < 0) continue;
    #pragma unroll
    for (int ctl = 0; ctl < 8; ++ctl)
      X0[(size_t)row * 128 + ctl * 16 + col0] = f2bf(acc[ctl][rr]);
  }
}

// ---------------------------------------------------------------------------
// scans over joint [0,S): scanA block sums; scanC3 fuses the block-offset
// scan.  offs[E..S) land in [NNZ,2NNZ) automatically.
// ---------------------------------------------------------------------------
__global__ __launch_bounds__(256) void k_scanA(const int* __restrict__ cnt, int S,
                                               int* __restrict__ bsum){
  __shared__ int sh[256];
  int base = blockIdx.x * 1024 + threadIdx.x * 4;
  int s = 0;
  #pragma unroll
  for (int k = 0; k < 4; ++k){ int idx = base + k; if (idx < S) s += cnt[idx]; }
  sh[threadIdx.x] = s; __syncthreads();
  for (int off = 128; off > 0; off >>= 1){
    if (threadIdx.x < off) sh[threadIdx.x] += sh[threadIdx.x + off];
    __syncthreads();
  }
  if (threadIdx.x == 0) bsum[blockIdx.x] = sh[0];
}

__global__ __launch_bounds__(256) void k_scanC3(const int* __restrict__ cnt, int S,
    const int* __restrict__ bsum, int nb, int* __restrict__ offs){
  __shared__ int shb[256];
  __shared__ int sh[256];
  int t = threadIdx.x;
  int b = (int)blockIdx.x;
  shb[t] = (t < nb) ? bsum[t] : 0;
  __syncthreads();
  for (int off = 1; off < 256; off <<= 1){
    int v = (t >= off) ? shb[t - off] : 0; __syncthreads();
    shb[t] += v; __syncthreads();
  }
  int bbase = (b == 0) ? 0 : shb[b - 1];           // exclusive block prefix
  int base = b * 1024 + t * 4;
  int c[4]; int s = 0;
  #pragma unroll
  for (int k = 0; k < 4; ++k){ int idx = base + k; c[k] = (idx < S) ? cnt[idx] : 0; s += c[k]; }
  sh[t] = s; __syncthreads();
  for (int off = 1; off < 256; off <<= 1){
    int v = (t >= off) ? sh[t - off] : 0; __syncthreads();
    sh[t] += v; __syncthreads();
  }
  int run = bbase + sh[t] - s;                     // exclusive prefix for this thread
  #pragma unroll
  for (int k = 0; k < 4; ++k){
    int idx = base + k;
    if (idx < S){ offs[idx] = run; run += c[k]; }
  }
}

// ---------------------------------------------------------------------------
// place_e: pure scatter (rank precomputed), zero atomics.
// ---------------------------------------------------------------------------
__global__ __launch_bounds__(256) void k_place_e(
    const int* __restrict__ edges, const int* __restrict__ vertex, int NNZ,
    const int* __restrict__ offs, const int* __restrict__ rank_e,
    int* __restrict__ rows){
  int i = (int)blockIdx.x * 256 + (int)threadIdx.x;
  if (i < NNZ) rows[offs[edges[i]] + rank_e[i]] = vertex[i];
}

// ---------------------------------------------------------------------------
// seg_body v4 (exact R4/R5/R9/R10-proven 2-deep version).
// ---------------------------------------------------------------------------
template<int OUT_BF16>
__device__ __forceinline__ void seg_body(const uint4* __restrict__ feat,
    const float* __restrict__ att, const int* __restrict__ rows_sorted,
    const int* __restrict__ offs, const int* __restrict__ cnt,
    const int* __restrict__ stype, void* __restrict__ outbuf,
    int S, int blockId, int tid){
  int wid = tid >> 6, lane = tid & 63;
  int s = blockId * 4 + wid;
  if (s >= S) return;
  int t = stype[s];
  int sub = lane >> 4, lane16 = lane & 15;         // sub-wave row slot, lane-in-row
  const float4* ap = (const float4*)(att + t * 128 + lane16 * 8);
  float4 A0 = ap[0], A1 = ap[1];
  int start = offs[s], len = cnt[s];
  float denom = 0.f;
  float acc[8];
  #pragma unroll
  for (int e = 0; e < 8; ++e) acc[e] = 0.f;

  for (int base = 0; base < len; base += 64){
    int m = len - base; if (m > 64) m = 64;
    int idx = 0;                                   // lanes >= m: safe dummy (row 0)
    if (lane < m) idx = rows_sorted[start + base + lane];
    int ng = (m + 3) >> 2;                         // groups of 4 rows
    uint4 uA = make_uint4(0,0,0,0), uB = make_uint4(0,0,0,0);
    {
      int r0 = __shfl(idx, sub);                   // uniform flow
      if (sub < m) uA = feat[(size_t)r0 * 16 + lane16];
      int r1 = __shfl(idx, 4 + sub);               // uniform flow
      if (4 + sub < m) uB = feat[(size_t)r1 * 16 + lane16];
    }
    for (int g = 0; g < ng; g += 2){
      {
        uint4 u = uA;
        int nr = (g + 2) * 4 + sub;
        int rn = __shfl(idx, nr & 63);             // UNCONDITIONAL (uniform)
        if (nr < m) uA = feat[(size_t)rn * 16 + lane16];  // load-only guard
        float x0 = bflo(u.x), x1 = bfhi(u.x), x2 = bflo(u.y), x3 = bfhi(u.y);
        float x4 = bflo(u.z), x5 = bfhi(u.z), x6 = bflo(u.w), x7 = bfhi(u.w);
        float p = x0*A0.x + x1*A0.y + x2*A0.z + x3*A0.w
                + x4*A1.x + x5*A1.y + x6*A1.z + x7*A1.w;
        p += __shfl_xor(p, 1);                     // complete 16-chan head dot
        float wgt = __expf(lrelu(p));
        wgt = (g * 4 + sub < m) ? wgt : 0.f;       // mask pad rows (exp(0)=1!)
        denom += wgt;
        acc[0] += wgt*x0; acc[1] += wgt*x1; acc[2] += wgt*x2; acc[3] += wgt*x3;
        acc[4] += wgt*x4; acc[5] += wgt*x5; acc[6] += wgt*x6; acc[7] += wgt*x7;
      }
      if (g + 1 < ng){                             // ng uniform -> uniform branch
        uint4 u = uB;
        int nr = (g + 3) * 4 + sub;
        int rn = __shfl(idx, nr & 63);             // UNCONDITIONAL (uniform)
        if (nr < m) uB = feat[(size_t)rn * 16 + lane16];
        float x0 = bflo(u.x), x1 = bfhi(u.x), x2 = bflo(u.y), x3 = bfhi(u.y);
        float x4 = bflo(u.z), x5 = bfhi(u.z), x6 = bflo(u.w), x7 = bfhi(u.w);
        float p = x0*A0.x + x1*A0.y + x2*A0.z + x3*A0.w
                + x4*A1.x + x5*A1.y + x6*A1.z + x7*A1.w;
        p += __shfl_xor(p, 1);
        float wgt = __expf(lrelu(p));
        wgt = ((g + 1) * 4 + sub < m) ? wgt : 0.f;
        denom += wgt;
        acc[0] += wgt*x0; acc[1] += wgt*x1; acc[2] += wgt*x2; acc[3] += wgt*x3;
        acc[4] += wgt*x4; acc[5] += wgt*x5; acc[6] += wgt*x6; acc[7] += wgt*x7;
      }
    }
  }
  // cross-sub-wave reduction (same lane16 <-> same head)
  denom += __shfl_xor(denom, 16);
  denom += __shfl_xor(denom, 32);
  #pragma unroll
  for (int e = 0; e < 8; ++e){
    acc[e] += __shfl_xor(acc[e], 16);
    acc[e] += __shfl_xor(acc[e], 32);
  }
  float inv = 1.f / (denom + 1e-16f);
  float v[8];
  #pragma unroll
  for (int e = 0; e < 8; ++e) v[e] = acc[e] * inv;

  if constexpr (OUT_BF16){
    if (sub == 0){
      uint4 pw;
      pw.x = (unsigned)f2bf(fmaxf(v[0],0.f)) | ((unsigned)f2bf(fmaxf(v[1],0.f)) << 16);
      pw.y = (unsigned)f2bf(fmaxf(v[2],0.f)) | ((unsigned)f2bf(fmaxf(v[3],0.f)) << 16);
      pw.z = (unsigned)f2bf(fmaxf(v[4],0.f)) | ((unsigned)f2bf(fmaxf(v[5],0.f)) << 16);
      pw.w = (unsigned)f2bf(fmaxf(v[6],0.f)) | ((unsigned)f2bf(fmaxf(v[7],0.f)) << 16);
      ((uint4*)outbuf)[(size_t)s * 16 + lane16] = pw;
    }
  } else {
    if (sub == 0){
      float4* op = (float4*)outbuf;
      op[(size_t)s * 32 + lane16 * 2]     = make_float4(v[0], v[1], v[2], v[3]);
      op[(size_t)s * 32 + lane16 * 2 + 1] = make_float4(v[4], v[5], v[6], v[7]);
    }
  }
}

// ---------------------------------------------------------------------------
// K_B: [place_v | seg1], period 5 (r0 place_v scatter, r1-4 seg1).
// ---------------------------------------------------------------------------
__global__ __launch_bounds__(256) void k_seg1_pv(
    const int* __restrict__ edges, const int* __restrict__ vertex, int NNZ,
    const int* __restrict__ offs, const int* __restrict__ rank_v,
    int* __restrict__ rows, int E, int nbPlace,
    const uint4* __restrict__ X0, const float* __restrict__ att_e,
    const int* __restrict__ cnt, const int* __restrict__ etype,
    void* __restrict__ Xe, int nbSeg){
  const int q = (int)blockIdx.x / 5, r = (int)blockIdx.x % 5;
  if (r == 0){
    if (q < nbPlace){
      int i = q * 256 + (int)threadIdx.x;
      if (i < NNZ) rows[offs[E + vertex[i]] + rank_v[i]] = edges[i];
    }
    return;
  }
  int segBlk = q * 4 + (r - 1);
  if (segBlk >= nbSeg) return;
  seg_body<1>(X0, att_e, rows, offs, cnt, etype, Xe, E, segBlk, threadIdx.x);
}

__global__ __launch_bounds__(256) void k_seg2(const uint4* __restrict__ Xe,
    const float* __restrict__ att_v, const int* __restrict__ rows,
    const int* __restrict__ offs, const int* __restrict__ cnt,
    const int* __restrict__ vtype, float* __restrict__ out, int N){
  seg_body<0>(Xe, att_v, rows, offs, cnt, vtype, out, N,
              (int)blockIdx.x, threadIdx.x);
}

extern "C" void kernel_launch(void* const* d_in, const int* in_sizes, int n_in,
                              void* d_out, int out_size, void* d_ws, size_t ws_size,
                              hipStream_t stream){
  const float* X      = (const float*)d_in[0];
  const float* W      = (const float*)d_in[1];
  const float* att_e  = (const float*)d_in[2];
  const float* att_v  = (const float*)d_in[3];
  const int*   vertex = (const int*)d_in[4];
  const int*   edges  = (const int*)d_in[5];
  const int*   vtype  = (const int*)d_in[6];
  const int*   etype  = (const int*)d_in[7];
  float* out = (float*)d_out;
  const int N   = in_sizes[0] / 128;
  const int NNZ = in_sizes[4];
  const int E   = in_sizes[7];
  const int S   = E + N;

  const int nbI = (NNZ + 255) / 256;                  // place blocks
  const int nbHN = (N + 255) / 256;                   // type-hist blocks
  const int nbS = (S + 1023) / 1024;                  // joint-scan blocks
  const int nbSeg1 = (E + 3) / 4;                     // seg1 blocks
  const int nbPad = (N + 252 + 63) / 64;              // padded gemm blocks
  const int nsortedCap = nbPad * 64;                  // FULL gemm-grid coverage
  const int nQB = (nbI > (nbSeg1 + 3) / 4) ? nbI : (nbSeg1 + 3) / 4;

  // workspace carve (~52.9MB)
  char* wp = (char*)d_ws;
  int* cnt    = (int*)wp; wp += (size_t)S * 4;        // [0,E) edge, [E,S) vertex
  int* tcnt   = (int*)wp; wp += 16;                   // node-type counts
  int* tcur   = (int*)wp; wp += 16;                   // node-type cursors
  int* offs   = (int*)wp; wp += (size_t)S * 4;        // joint scan; offs[E..S) in [NNZ,2NNZ)
  int* bsum   = (int*)wp; wp += 1024;                 // up to 256 block sums
  int* rows   = (int*)wp; wp += (size_t)2 * NNZ * 4;  // [0,NNZ) edge-grp, [NNZ,2NNZ) vtx-grp
  int* nsorted= (int*)wp; wp += (size_t)nsortedCap * 4; // type-sorted node ids (pad = -1)
  int* rank_e = (int*)wp; wp += (size_t)NNZ * 4;      // within-edge-key arrival rank
  int* rank_v = (int*)wp; wp += (size_t)NNZ * 4;      // within-vtx-key arrival rank
  unsigned short* X0 = (unsigned short*)wp; wp += (size_t)N * 128 * 2;
  unsigned short* Xe = (unsigned short*)wp; wp += (size_t)E * 128 * 2;
  short* Bfrag = (short*)wp; wp += (size_t)65536 * 2;

  hipMemsetAsync(cnt, 0, (size_t)(S + 8) * 4, stream);          // cnt + tcnt + tcur
  hipMemsetAsync(nsorted, 0xFF, (size_t)nsortedCap * 4, stream); // -1 sentinels

  // prep: type-hist + Bfrag pack; node placement (pbase inline from tcnt)
  k_prep<<<nbHN + 256, 256, 0, stream>>>(vtype, N, tcnt, nbHN, W, Bfrag);
  k_nodeplace<<<nbHN, 256, 0, stream>>>(vtype, N, tcnt, tcur, nsorted);

  // K_A: gemm + LDS-bucketed hist (no global atomics); hist blocks first
  k_gemm_hist<<<2 * NB_H + nbPad, 256, 0, stream>>>(X, Bfrag, nsorted, tcnt,
      (unsigned short*)X0, edges, vertex, NNZ, cnt, E, N, rank_e, rank_v);

  // joint scan (2 launches) + edge-side placement
  k_scanA<<<nbS, 256, 0, stream>>>(cnt, S, bsum);
  k_scanC3<<<nbS, 256, 0, stream>>>(cnt, S, bsum, nbS, offs);
  k_place_e<<<nbI, 256, 0, stream>>>(edges, vertex, NNZ, offs, rank_e, rows);

  // K_B: seg1 overlapped with vertex-side placement (period 5, atomic-free)
  k_seg1_pv<<<5 * nQB, 256, 0, stream>>>(edges, vertex, NNZ, offs, rank_v,
      rows, E, nbI, (const uint4*)X0, att_e, cnt, etype, Xe, nbSeg1);

  k_seg2<<<(N + 3) / 4, 256, 0, stream>>>((const uint4*)Xe, att_v,
      rows, offs + E, cnt + E, vtype, out, N);
}

// Round 12
// 328.795 us; speedup vs baseline: 2.1908x; 2.1908x over previous
//
#include <hip/hip_runtime.h>

typedef __attribute__((ext_vector_type(8))) short bf16x8;
typedef __attribute__((ext_vector_type(4))) float f32x4;

#define NEG_SLOPE 0.2f

__device__ __forceinline__ unsigned short f2bf(float f){
  unsigned u = __float_as_uint(f);
  u = (u + 0x7fffu + ((u >> 16) & 1u)) >> 16;   // RNE
  return (unsigned short)u;
}
__device__ __forceinline__ float bflo(unsigned u){ return __uint_as_float(u << 16); }
__device__ __forceinline__ float bfhi(unsigned u){ return __uint_as_float(u & 0xffff0000u); }
__device__ __forceinline__ float lrelu(float x){ return x > 0.f ? x : NEG_SLOPE * x; }

// ---------------------------------------------------------------------------
// K0: [typehist | bprep].
// ---------------------------------------------------------------------------
__global__ __launch_bounds__(256) void k_prep(
    const int* __restrict__ vtype, int N, int* __restrict__ tcnt, int nbHN,
    const float* __restrict__ W, short* __restrict__ Bfrag){
  __shared__ int lcnt[4];
  int b = (int)blockIdx.x;
  if (b < nbHN){
    if (threadIdx.x < 4) lcnt[threadIdx.x] = 0;
    __syncthreads();
    int i = b * 256 + threadIdx.x;
    if (i < N) atomicAdd(&lcnt[vtype[i]], 1);
    __syncthreads();
    if (threadIdx.x < 4 && lcnt[threadIdx.x] > 0)
      atomicAdd(tcnt + threadIdx.x, lcnt[threadIdx.x]);
    return;
  }
  b -= nbHN;
  int u = b * 256 + threadIdx.x;                   // 0..65535
  int j = u & 7, lane = (u >> 3) & 63, ct = (u >> 9) & 31, ks = u >> 14;
  int k = ks * 32 + ((lane >> 4) << 3) + j;
  int col = (ct << 4) + (lane & 15);
  int t = col >> 7, o = col & 127;
  Bfrag[u] = (short)f2bf(W[(t * 128 + k) * 128 + o]);
}

// ---------------------------------------------------------------------------
// node placement; padded bucket bases derived inline from tcnt.
// ---------------------------------------------------------------------------
__global__ __launch_bounds__(256) void k_nodeplace(
    const int* __restrict__ vtype, int N, const int* __restrict__ tcnt,
    int* __restrict__ tcur, int* __restrict__ nsorted){
  __shared__ int lcnt[4];
  __shared__ int gbase[4];
  __shared__ int spb[4];
  int t = threadIdx.x;
  if (t < 4) lcnt[t] = 0;
  if (t == 0){
    int run = 0;
    #pragma unroll
    for (int k = 0; k < 4; ++k){ spb[k] = run; run += ((tcnt[k] + 63) >> 6) << 6; }
  }
  __syncthreads();
  int i = (int)blockIdx.x * 256 + t;
  int tt = 0, rank = 0;
  bool valid = i < N;
  if (valid){ tt = vtype[i]; rank = atomicAdd(&lcnt[tt], 1); }
  __syncthreads();
  if (t < 4 && lcnt[t] > 0) gbase[t] = atomicAdd(tcur + t, lcnt[t]);
  __syncthreads();
  if (valid) nsorted[spb[tt] + gbase[tt] + rank] = i;
}

// ---------------------------------------------------------------------------
// K_A: [gemm+We | hist_both], period 3.  R12: R10's proven structure (R11's
// LDS-bucket hist was 510us — 16x read amplification at 128-wave parallelism;
// global-atomic hist at 74us IS the floor).  NEW: gemm epilogue precomputes
// We[node][4 etypes][8 heads] = exp(leaky(dot(acc_f32, att_e))) as bf16 —
// rides FREE under the 74us hist bound, and removes dot/shfl/exp from seg1's
// per-incidence loop (8x amortization: N=100k vs NNZ=800k).
// R1-R3's failure was the divergent-shfl bug (proven by R3 bisect), NOT this
// epilogue — reviving it with R4's uniform-shfl discipline.
// ---------------------------------------------------------------------------
__global__ __launch_bounds__(256, 3) void k_gemm_hist(const float* __restrict__ X,
    const short* __restrict__ Bfrag, const int* __restrict__ nsorted,
    const int* __restrict__ tcnt, unsigned short* __restrict__ X0,
    const int* __restrict__ edges, const int* __restrict__ vertex, int NNZ,
    int* __restrict__ cnt, int E,
    int* __restrict__ rank_e, int* __restrict__ rank_v, int nbHist,
    const float* __restrict__ att_e, unsigned short* __restrict__ We){
  __shared__ __align__(16) short shB[16896];       // 32KB slab / 33792B shF
  __shared__ __align__(16) float shAtt[512];
  const int tid = threadIdx.x;
  const int q = (int)blockIdx.x / 3, r = (int)blockIdx.x % 3;

  if (r != 0){                                     // hist role: 1 incid/thread
    int hb = 2 * q + (r - 1);
    if (hb < nbHist){
      int i = hb * 256 + tid;
      if (i < NNZ){
        rank_e[i] = atomicAdd(cnt + edges[i], 1);
        rank_v[i] = atomicAdd(cnt + E + vertex[i], 1);
      }
    }
    return;
  }

  const int rowIdx = q * 64;
  int pb1, pb2, pb3;
  {
    int run = ((tcnt[0] + 63) >> 6) << 6; pb1 = run;
    run    += ((tcnt[1] + 63) >> 6) << 6; pb2 = run;
    run    += ((tcnt[2] + 63) >> 6) << 6; pb3 = run;
  }
  const int t = (rowIdx >= pb1) + (rowIdx >= pb2) + (rowIdx >= pb3);

  shAtt[tid] = att_e[tid];
  shAtt[tid + 256] = att_e[tid + 256];

  // stage this type's full B (8 ct x 4 ks x 64 lanes, bf16x8 units)
  const bf16x8* Bv = (const bf16x8*)Bfrag;
  bf16x8* shBv = (bf16x8*)shB;
  #pragma unroll
  for (int v = 0; v < 8; ++v){
    int item = v * 256 + tid;                      // 0..2047
    int slab = item >> 6, ln = item & 63;          // slab = ks*8 + ctl
    int ks = slab >> 3, ctl = slab & 7;
    shBv[item] = Bv[((ks * 32 + 8 * t + ctl) * 64) + ln];
  }

  const int w = tid >> 6, lane = tid & 63;
  const int m = lane & 15, qq = lane >> 4;
  const int node = nsorted[rowIdx + w * 16 + m];   // -1 = pad sentinel

  bf16x8 afrag[4];
  #pragma unroll
  for (int ks = 0; ks < 4; ++ks){
    bf16x8 f;
    if (node >= 0){
      const float4* src = (const float4*)(X + (size_t)node * 128 + ks * 32 + qq * 8);
      float4 a = src[0], bq = src[1];
      f[0]=(short)f2bf(a.x); f[1]=(short)f2bf(a.y); f[2]=(short)f2bf(a.z); f[3]=(short)f2bf(a.w);
      f[4]=(short)f2bf(bq.x); f[5]=(short)f2bf(bq.y); f[6]=(short)f2bf(bq.z); f[7]=(short)f2bf(bq.w);
    } else {
      #pragma unroll
      for (int z = 0; z < 8; ++z) f[z] = 0;
    }
    afrag[ks] = f;
  }

  f32x4 acc[8];
  #pragma unroll
  for (int ct = 0; ct < 8; ++ct){
    acc[ct][0]=0.f; acc[ct][1]=0.f; acc[ct][2]=0.f; acc[ct][3]=0.f;
  }

  __syncthreads();
  #pragma unroll
  for (int ctl = 0; ctl < 8; ++ctl){
    #pragma unroll
    for (int ks = 0; ks < 4; ++ks){
      bf16x8 bf = shBv[(ks * 8 + ctl) * 64 + lane];
      acc[ctl] = __builtin_amdgcn_mfma_f32_16x16x32_bf16(afrag[ks], bf, acc[ctl], 0, 0, 0);
    }
  }

  const int col0 = lane & 15;
  #pragma unroll
  for (int rr = 0; rr < 4; ++rr){
    int row = nsorted[rowIdx + w * 16 + qq * 4 + rr];
    if (row < 0) continue;
    #pragma unroll
    for (int ctl = 0; ctl < 8; ++ctl)
      X0[(size_t)row * 128 + ctl * 16 + col0] = f2bf(acc[ctl][rr]);
  }

  // ---- We epilogue: per-node softmax weights for all 4 edge types ----
  __syncthreads();                                 // B slab no longer needed
  float* shF = (float*)shB;                        // 64 x 132 fp32 (pad stride)
  #pragma unroll
  for (int ctl = 0; ctl < 8; ++ctl){
    #pragma unroll
    for (int rr = 0; rr < 4; ++rr)
      shF[(w * 16 + qq * 4 + rr) * 132 + ctl * 16 + col0] = acc[ctl][rr];
  }
  __syncthreads();
  const int prow = tid >> 2, part = tid & 3;       // row 0..63, head-pair 2*part
  const int pnode = nsorted[rowIdx + prow];
  if (pnode >= 0){
    const float4* xr = (const float4*)(shF + prow * 132 + part * 32);
    float4 xv[8];
    #pragma unroll
    for (int i = 0; i < 8; ++i) xv[i] = xr[i];
    #pragma unroll
    for (int tt = 0; tt < 4; ++tt){
      const float4* ae = (const float4*)(shAtt + tt * 128 + part * 32);
      float s0 = 0.f, s1 = 0.f;
      #pragma unroll
      for (int i = 0; i < 4; ++i){
        float4 a = ae[i], b = ae[4 + i];
        s0 += xv[i].x*a.x + xv[i].y*a.y + xv[i].z*a.z + xv[i].w*a.w;
        s1 += xv[4+i].x*b.x + xv[4+i].y*b.y + xv[4+i].z*b.z + xv[4+i].w*b.w;
      }
      float w0 = __expf(lrelu(s0)), w1 = __expf(lrelu(s1));
      ((unsigned*)We)[(size_t)pnode * 16 + tt * 4 + part] =
          (unsigned)f2bf(w0) | ((unsigned)f2bf(w1) << 16);
    }
  }
}

// ---------------------------------------------------------------------------
// scans over joint [0,S).
// ---------------------------------------------------------------------------
__global__ __launch_bounds__(256) void k_scanA(const int* __restrict__ cnt, int S,
                                               int* __restrict__ bsum){
  __shared__ int sh[256];
  int base = blockIdx.x * 1024 + threadIdx.x * 4;
  int s = 0;
  #pragma unroll
  for (int k = 0; k < 4; ++k){ int idx = base + k; if (idx < S) s += cnt[idx]; }
  sh[threadIdx.x] = s; __syncthreads();
  for (int off = 128; off > 0; off >>= 1){
    if (threadIdx.x < off) sh[threadIdx.x] += sh[threadIdx.x + off];
    __syncthreads();
  }
  if (threadIdx.x == 0) bsum[blockIdx.x] = sh[0];
}

__global__ __launch_bounds__(256) void k_scanC3(const int* __restrict__ cnt, int S,
    const int* __restrict__ bsum, int nb, int* __restrict__ offs){
  __shared__ int shb[256];
  __shared__ int sh[256];
  int t = threadIdx.x;
  int b = (int)blockIdx.x;
  shb[t] = (t < nb) ? bsum[t] : 0;
  __syncthreads();
  for (int off = 1; off < 256; off <<= 1){
    int v = (t >= off) ? shb[t - off] : 0; __syncthreads();
    shb[t] += v; __syncthreads();
  }
  int bbase = (b == 0) ? 0 : shb[b - 1];           // exclusive block prefix
  int base = b * 1024 + t * 4;
  int c[4]; int s = 0;
  #pragma unroll
  for (int k = 0; k < 4; ++k){ int idx = base + k; c[k] = (idx < S) ? cnt[idx] : 0; s += c[k]; }
  sh[t] = s; __syncthreads();
  for (int off = 1; off < 256; off <<= 1){
    int v = (t >= off) ? sh[t - off] : 0; __syncthreads();
    sh[t] += v; __syncthreads();
  }
  int run = bbase + sh[t] - s;                     // exclusive prefix for this thread
  #pragma unroll
  for (int k = 0; k < 4; ++k){
    int idx = base + k;
    if (idx < S){ offs[idx] = run; run += c[k]; }
  }
}

// ---------------------------------------------------------------------------
// place_e: pure scatter (rank precomputed), zero atomics.
// ---------------------------------------------------------------------------
__global__ __launch_bounds__(256) void k_place_e(
    const int* __restrict__ edges, const int* __restrict__ vertex, int NNZ,
    const int* __restrict__ offs, const int* __restrict__ rank_e,
    int* __restrict__ rows){
  int i = (int)blockIdx.x * 256 + (int)threadIdx.x;
  if (i < NNZ) rows[offs[edges[i]] + rank_e[i]] = vertex[i];
}

// ---------------------------------------------------------------------------
// seg_body v6: R4-proven uniform-shfl 2-deep pipeline + PRECOMPUTED bf16
// weights (wgt[r*32 + t*8 + head]) — no dot, no shfl_xor, no exp per row.
// Pad rows masked by w=0 propagation (prologue: w=0 unless sub<m; in-loop:
// w=0 when nr>=m) — mathematically identical to the post-exp mask.
// OUT_BF16 (seg1): also emits Wv[s][4 vtypes][8 heads] from post-relu v[].
// ---------------------------------------------------------------------------
template<int OUT_BF16>
__device__ __forceinline__ void seg_body(const uint4* __restrict__ feat,
    const unsigned short* __restrict__ wgt, const int* __restrict__ rows_sorted,
    const int* __restrict__ offs, const int* __restrict__ cnt,
    const int* __restrict__ stype, void* __restrict__ outbuf,
    int S, int blockId, int tid,
    const float* __restrict__ att_next, unsigned short* __restrict__ wnext){
  int wid = tid >> 6, lane = tid & 63;
  int s = blockId * 4 + wid;
  if (s >= S) return;
  int t = stype[s];
  int sub = lane >> 4, lane16 = lane & 15;         // sub-wave row slot, lane-in-row
  int toff = t * 8 + (lane16 >> 1);                // head = lane16>>1
  int start = offs[s], len = cnt[s];
  float denom = 0.f;
  float acc[8];
  #pragma unroll
  for (int e = 0; e < 8; ++e) acc[e] = 0.f;

  for (int base = 0; base < len; base += 64){
    int m = len - base; if (m > 64) m = 64;
    int idx = 0;                                   // lanes >= m: safe dummy (row 0)
    if (lane < m) idx = rows_sorted[start + base + lane];
    int ng = (m + 3) >> 2;                         // groups of 4 rows
    uint4 uA = make_uint4(0,0,0,0), uB = make_uint4(0,0,0,0);
    float wA = 0.f, wB = 0.f;
    {
      int r0 = __shfl(idx, sub);                   // uniform flow
      if (sub < m){ uA = feat[(size_t)r0 * 16 + lane16];
                    wA = bflo((unsigned)wgt[(size_t)r0 * 32 + toff]); }
      int r1 = __shfl(idx, 4 + sub);               // uniform flow
      if (4 + sub < m){ uB = feat[(size_t)r1 * 16 + lane16];
                        wB = bflo((unsigned)wgt[(size_t)r1 * 32 + toff]); }
    }
    for (int g = 0; g < ng; g += 2){
      {
        uint4 u = uA; float w = wA;
        int nr = (g + 2) * 4 + sub;
        int rn = __shfl(idx, nr & 63);             // UNCONDITIONAL (uniform)
        if (nr < m){ uA = feat[(size_t)rn * 16 + lane16];
                     wA = bflo((unsigned)wgt[(size_t)rn * 32 + toff]); }
        else wA = 0.f;                             // stale u harmless: w=0
        denom += w;
        acc[0] += w * bflo(u.x); acc[1] += w * bfhi(u.x);
        acc[2] += w * bflo(u.y); acc[3] += w * bfhi(u.y);
        acc[4] += w * bflo(u.z); acc[5] += w * bfhi(u.z);
        acc[6] += w * bflo(u.w); acc[7] += w * bfhi(u.w);
      }
      if (g + 1 < ng){                             // ng uniform -> uniform branch
        uint4 u = uB; float w = wB;
        int nr = (g + 3) * 4 + sub;
        int rn = __shfl(idx, nr & 63);             // UNCONDITIONAL (uniform)
        if (nr < m){ uB = feat[(size_t)rn * 16 + lane16];
                     wB = bflo((unsigned)wgt[(size_t)rn * 32 + toff]); }
        else wB = 0.f;
        denom += w;
        acc[0] += w * bflo(u.x); acc[1] += w * bfhi(u.x);
        acc[2] += w * bflo(u.y); acc[3] += w * bfhi(u.y);
        acc[4] += w * bflo(u.z); acc[5] += w * bfhi(u.z);
        acc[6] += w * bflo(u.w); acc[7] += w * bfhi(u.w);
      }
    }
  }
  // cross-sub-wave reduction (same lane16 <-> same head); butterfly -> all lanes
  denom += __shfl_xor(denom, 16);
  denom += __shfl_xor(denom, 32);
  #pragma unroll
  for (int e = 0; e < 8; ++e){
    acc[e] += __shfl_xor(acc[e], 16);
    acc[e] += __shfl_xor(acc[e], 32);
  }
  float inv = 1.f / (denom + 1e-16f);
  float v[8];
  #pragma unroll
  for (int e = 0; e < 8; ++e) v[e] = acc[e] * inv;

  if constexpr (OUT_BF16){
    #pragma unroll
    for (int e = 0; e < 8; ++e) v[e] = fmaxf(v[e], 0.f);   // relu (edge feats)
    // Wv epilogue: FULL uniform flow (all 64 lanes compute; sub-0 even lanes store)
    #pragma unroll
    for (int tt = 0; tt < 4; ++tt){
      const float* av = att_next + tt * 128 + lane16 * 8;
      float p = v[0]*av[0] + v[1]*av[1] + v[2]*av[2] + v[3]*av[3]
              + v[4]*av[4] + v[5]*av[5] + v[6]*av[6] + v[7]*av[7];
      p += __shfl_xor(p, 1);                       // complete 16-chan head dot
      float wv = __expf(lrelu(p));
      if (sub == 0 && (lane16 & 1) == 0)
        wnext[(size_t)s * 32 + tt * 8 + (lane16 >> 1)] = f2bf(wv);
    }
    if (sub == 0){
      uint4 pw;
      pw.x = (unsigned)f2bf(v[0]) | ((unsigned)f2bf(v[1]) << 16);
      pw.y = (unsigned)f2bf(v[2]) | ((unsigned)f2bf(v[3]) << 16);
      pw.z = (unsigned)f2bf(v[4]) | ((unsigned)f2bf(v[5]) << 16);
      pw.w = (unsigned)f2bf(v[6]) | ((unsigned)f2bf(v[7]) << 16);
      ((uint4*)outbuf)[(size_t)s * 16 + lane16] = pw;
    }
  } else {
    if (sub == 0){
      float4* op = (float4*)outbuf;
      op[(size_t)s * 32 + lane16 * 2]     = make_float4(v[0], v[1], v[2], v[3]);
      op[(size_t)s * 32 + lane16 * 2 + 1] = make_float4(v[4], v[5], v[6], v[7]);
    }
  }
}

// ---------------------------------------------------------------------------
// K_B: [place_v | seg1], period 5 (r0 place_v scatter, r1-4 seg1+Wv).
// ---------------------------------------------------------------------------
__global__ __launch_bounds__(256) void k_seg1_pv(
    const int* __restrict__ edges, const int* __restrict__ vertex, int NNZ,
    const int* __restrict__ offs, const int* __restrict__ rank_v,
    int* __restrict__ rows, int E, int nbPlace,
    const uint4* __restrict__ X0, const unsigned short* __restrict__ We,
    const int* __restrict__ cnt, const int* __restrict__ etype,
    void* __restrict__ Xe, int nbSeg,
    const float* __restrict__ att_v, unsigned short* __restrict__ Wv){
  const int q = (int)blockIdx.x / 5, r = (int)blockIdx.x % 5;
  if (r == 0){
    if (q < nbPlace){
      int i = q * 256 + (int)threadIdx.x;
      if (i < NNZ) rows[offs[E + vertex[i]] + rank_v[i]] = edges[i];
    }
    return;
  }
  int segBlk = q * 4 + (r - 1);
  if (segBlk >= nbSeg) return;
  seg_body<1>(X0, We, rows, offs, cnt, etype, Xe, E, segBlk, threadIdx.x,
              att_v, Wv);
}

__global__ __launch_bounds__(256) void k_seg2(const uint4* __restrict__ Xe,
    const unsigned short* __restrict__ Wv, const int* __restrict__ rows,
    const int* __restrict__ offs, const int* __restrict__ cnt,
    const int* __restrict__ vtype, float* __restrict__ out, int N){
  seg_body<0>(Xe, Wv, rows, offs, cnt, vtype, out, N,
              (int)blockIdx.x, threadIdx.x, nullptr, nullptr);
}

extern "C" void kernel_launch(void* const* d_in, const int* in_sizes, int n_in,
                              void* d_out, int out_size, void* d_ws, size_t ws_size,
                              hipStream_t stream){
  const float* X      = (const float*)d_in[0];
  const float* W      = (const float*)d_in[1];
  const float* att_e  = (const float*)d_in[2];
  const float* att_v  = (const float*)d_in[3];
  const int*   vertex = (const int*)d_in[4];
  const int*   edges  = (const int*)d_in[5];
  const int*   vtype  = (const int*)d_in[6];
  const int*   etype  = (const int*)d_in[7];
  float* out = (float*)d_out;
  const int N   = in_sizes[0] / 128;
  const int NNZ = in_sizes[4];
  const int E   = in_sizes[7];
  const int S   = E + N;

  const int nbI = (NNZ + 255) / 256;                  // hist/place blocks
  const int nbHN = (N + 255) / 256;                   // type-hist blocks
  const int nbS = (S + 1023) / 1024;                  // joint-scan blocks
  const int nbSeg1 = (E + 3) / 4;                     // seg1 blocks
  const int nbPad = (N + 252 + 63) / 64;              // padded gemm blocks
  const int nsortedCap = nbPad * 64;                  // FULL gemm-grid coverage
  const int nQA = (nbPad > (nbI + 1) / 2) ? nbPad : (nbI + 1) / 2;
  const int nQB = (nbI > (nbSeg1 + 3) / 4) ? nbI : (nbSeg1 + 3) / 4;

  // workspace carve (~59.3MB: R10's 52.9 + We 6.4; Wv overlays dead rank_e)
  char* wp = (char*)d_ws;
  int* cnt    = (int*)wp; wp += (size_t)S * 4;        // [0,E) edge, [E,S) vertex
  int* tcnt   = (int*)wp; wp += 16;                   // node-type counts
  int* tcur   = (int*)wp; wp += 16;                   // node-type cursors
  int* offs   = (int*)wp; wp += (size_t)S * 4;        // joint scan; offs[E..S) in [NNZ,2NNZ)
  int* bsum   = (int*)wp; wp += 1024;                 // up to 256 block sums
  int* rows   = (int*)wp; wp += (size_t)2 * NNZ * 4;  // [0,NNZ) edge-grp, [NNZ,2NNZ) vtx-grp
  int* nsorted= (int*)wp; wp += (size_t)nsortedCap * 4; // type-sorted node ids (pad = -1)
  int* rank_e = (int*)wp; wp += (size_t)NNZ * 4;      // rank_e; REUSED as Wv after place_e
  int* rank_v = (int*)wp; wp += (size_t)NNZ * 4;      // within-vtx-key arrival rank
  unsigned short* X0 = (unsigned short*)wp; wp += (size_t)N * 128 * 2;
  unsigned short* Xe = (unsigned short*)wp; wp += (size_t)E * 128 * 2;
  short* Bfrag = (short*)wp; wp += (size_t)65536 * 2;
  unsigned short* We = (unsigned short*)wp; wp += (size_t)N * 32 * 2;  // bf16 weights
  unsigned short* Wv = (unsigned short*)rank_e;       // E*32*2 = NNZ*4 bytes exactly

  hipMemsetAsync(cnt, 0, (size_t)(S + 8) * 4, stream);          // cnt + tcnt + tcur
  hipMemsetAsync(nsorted, 0xFF, (size_t)nsortedCap * 4, stream); // -1 sentinels

  // prep: type-hist + Bfrag pack; node placement (pbase inline from tcnt)
  k_prep<<<nbHN + 256, 256, 0, stream>>>(vtype, N, tcnt, nbHN, W, Bfrag);
  k_nodeplace<<<nbHN, 256, 0, stream>>>(vtype, N, tcnt, tcur, nsorted);

  // K_A: gemm+We epilogue overlapped with both hists (period 3)
  k_gemm_hist<<<3 * nQA, 256, 0, stream>>>(X, Bfrag, nsorted, tcnt,
      (unsigned short*)X0, edges, vertex, NNZ, cnt, E, rank_e, rank_v, nbI,
      att_e, We);

  // joint scan (2 launches) + edge-side placement (rank_e last read here)
  k_scanA<<<nbS, 256, 0, stream>>>(cnt, S, bsum);
  k_scanC3<<<nbS, 256, 0, stream>>>(cnt, S, bsum, nbS, offs);
  k_place_e<<<nbI, 256, 0, stream>>>(edges, vertex, NNZ, offs, rank_e, rows);

  // K_B: seg1 (We-weighted, emits Wv) overlapped with vertex-side placement
  k_seg1_pv<<<5 * nQB, 256, 0, stream>>>(edges, vertex, NNZ, offs, rank_v,
      rows, E, nbI, (const uint4*)X0, We, cnt, etype, Xe, nbSeg1, att_v, Wv);

  k_seg2<<<(N + 3) / 4, 256, 0, stream>>>((const uint4*)Xe, Wv,
      rows, offs + E, cnt + E, vtype, out, N);
}

// Round 13
// 302.166 us; speedup vs baseline: 2.3838x; 1.0881x over previous
//
#include <hip/hip_runtime.h>

typedef __attribute__((ext_vector_type(8))) short bf16x8;
typedef __attribute__((ext_vector_type(4))) float f32x4;

#define NEG_SLOPE 0.2f

__device__ __forceinline__ unsigned short f2bf(float f){
  unsigned u = __float_as_uint(f);
  u = (u + 0x7fffu + ((u >> 16) & 1u)) >> 16;   // RNE
  return (unsigned short)u;
}
__device__ __forceinline__ float bflo(unsigned u){ return __uint_as_float(u << 16); }
__device__ __forceinline__ float bfhi(unsigned u){ return __uint_as_float(u & 0xffff0000u); }
__device__ __forceinline__ float lrelu(float x){ return x > 0.f ? x : NEG_SLOPE * x; }

// ---------------------------------------------------------------------------
// K0: [typehist | bprep].
// ---------------------------------------------------------------------------
__global__ __launch_bounds__(256) void k_prep(
    const int* __restrict__ vtype, int N, int* __restrict__ tcnt, int nbHN,
    const float* __restrict__ W, short* __restrict__ Bfrag){
  __shared__ int lcnt[4];
  int b = (int)blockIdx.x;
  if (b < nbHN){
    if (threadIdx.x < 4) lcnt[threadIdx.x] = 0;
    __syncthreads();
    int i = b * 256 + threadIdx.x;
    if (i < N) atomicAdd(&lcnt[vtype[i]], 1);
    __syncthreads();
    if (threadIdx.x < 4 && lcnt[threadIdx.x] > 0)
      atomicAdd(tcnt + threadIdx.x, lcnt[threadIdx.x]);
    return;
  }
  b -= nbHN;
  int u = b * 256 + threadIdx.x;                   // 0..65535
  int j = u & 7, lane = (u >> 3) & 63, ct = (u >> 9) & 31, ks = u >> 14;
  int k = ks * 32 + ((lane >> 4) << 3) + j;
  int col = (ct << 4) + (lane & 15);
  int t = col >> 7, o = col & 127;
  Bfrag[u] = (short)f2bf(W[(t * 128 + k) * 128 + o]);
}

// ---------------------------------------------------------------------------
// node placement; padded bucket bases derived inline from tcnt.
// ---------------------------------------------------------------------------
__global__ __launch_bounds__(256) void k_nodeplace(
    const int* __restrict__ vtype, int N, const int* __restrict__ tcnt,
    int* __restrict__ tcur, int* __restrict__ nsorted){
  __shared__ int lcnt[4];
  __shared__ int gbase[4];
  __shared__ int spb[4];
  int t = threadIdx.x;
  if (t < 4) lcnt[t] = 0;
  if (t == 0){
    int run = 0;
    #pragma unroll
    for (int k = 0; k < 4; ++k){ spb[k] = run; run += ((tcnt[k] + 63) >> 6) << 6; }
  }
  __syncthreads();
  int i = (int)blockIdx.x * 256 + t;
  int tt = 0, rank = 0;
  bool valid = i < N;
  if (valid){ tt = vtype[i]; rank = atomicAdd(&lcnt[tt], 1); }
  __syncthreads();
  if (t < 4 && lcnt[t] > 0) gbase[t] = atomicAdd(tcur + t, lcnt[t]);
  __syncthreads();
  if (valid) nsorted[spb[tt] + gbase[tt] + rank] = i;
}

// ---------------------------------------------------------------------------
// K_A: [gemm | hist_e ONLY], period 3.  R13: split-hist on R10's lean
// pipeline.  R12's weight tables regressed (extra dependent gather in a
// latency-bound loop) — seg_body reverted to proven v4.  R6 measured the
// split pieces (K_A_e < 56, seg1+histv rider = 56.3); R6 lost only via 5
// extra launches, which R10's fused scan/pbase removed.
// ---------------------------------------------------------------------------
__global__ __launch_bounds__(256, 3) void k_gemm_hist(const float* __restrict__ X,
    const short* __restrict__ Bfrag, const int* __restrict__ nsorted,
    const int* __restrict__ tcnt, unsigned short* __restrict__ X0,
    const int* __restrict__ edges, int NNZ,
    int* __restrict__ cnt, int* __restrict__ rank_e, int nbHist){
  __shared__ short shB[8 * 4 * 64 * 8];            // 32KB: type slab, frag order
  const int tid = threadIdx.x;
  const int q = (int)blockIdx.x / 3, r = (int)blockIdx.x % 3;

  if (r != 0){                                     // hist_e role: 1 incid/thread
    int hb = 2 * q + (r - 1);
    if (hb < nbHist){
      int i = hb * 256 + tid;
      if (i < NNZ) rank_e[i] = atomicAdd(cnt + edges[i], 1);
    }
    return;
  }

  const int rowIdx = q * 64;
  int pb1, pb2, pb3;
  {
    int run = ((tcnt[0] + 63) >> 6) << 6; pb1 = run;
    run    += ((tcnt[1] + 63) >> 6) << 6; pb2 = run;
    run    += ((tcnt[2] + 63) >> 6) << 6; pb3 = run;
  }
  const int t = (rowIdx >= pb1) + (rowIdx >= pb2) + (rowIdx >= pb3);

  // stage this type's full B (8 ct x 4 ks x 64 lanes, bf16x8 units)
  const bf16x8* Bv = (const bf16x8*)Bfrag;
  bf16x8* shBv = (bf16x8*)shB;
  #pragma unroll
  for (int v = 0; v < 8; ++v){
    int item = v * 256 + tid;                      // 0..2047
    int slab = item >> 6, ln = item & 63;          // slab = ks*8 + ctl
    int ks = slab >> 3, ctl = slab & 7;
    shBv[item] = Bv[((ks * 32 + 8 * t + ctl) * 64) + ln];
  }

  const int w = tid >> 6, lane = tid & 63;
  const int m = lane & 15, qq = lane >> 4;
  const int node = nsorted[rowIdx + w * 16 + m];   // -1 = pad sentinel

  bf16x8 afrag[4];
  #pragma unroll
  for (int ks = 0; ks < 4; ++ks){
    bf16x8 f;
    if (node >= 0){
      const float4* src = (const float4*)(X + (size_t)node * 128 + ks * 32 + qq * 8);
      float4 a = src[0], bq = src[1];
      f[0]=(short)f2bf(a.x); f[1]=(short)f2bf(a.y); f[2]=(short)f2bf(a.z); f[3]=(short)f2bf(a.w);
      f[4]=(short)f2bf(bq.x); f[5]=(short)f2bf(bq.y); f[6]=(short)f2bf(bq.z); f[7]=(short)f2bf(bq.w);
    } else {
      #pragma unroll
      for (int z = 0; z < 8; ++z) f[z] = 0;
    }
    afrag[ks] = f;
  }

  f32x4 acc[8];
  #pragma unroll
  for (int ct = 0; ct < 8; ++ct){
    acc[ct][0]=0.f; acc[ct][1]=0.f; acc[ct][2]=0.f; acc[ct][3]=0.f;
  }

  __syncthreads();
  #pragma unroll
  for (int ctl = 0; ctl < 8; ++ctl){
    #pragma unroll
    for (int ks = 0; ks < 4; ++ks){
      bf16x8 bf = shBv[(ks * 8 + ctl) * 64 + lane];
      acc[ctl] = __builtin_amdgcn_mfma_f32_16x16x32_bf16(afrag[ks], bf, acc[ctl], 0, 0, 0);
    }
  }

  const int col0 = lane & 15;
  #pragma unroll
  for (int rr = 0; rr < 4; ++rr){
    int row = nsorted[rowIdx + w * 16 + qq * 4 + rr];
    if (row < 0) continue;
    #pragma unroll
    for (int ctl = 0; ctl < 8; ++ctl)
      X0[(size_t)row * 128 + ctl * 16 + col0] = f2bf(acc[ctl][rr]);
  }
}

// ---------------------------------------------------------------------------
// scans (generic range, relative offsets): scanA block sums; scanC3 fuses
// the block-offset scan.
// ---------------------------------------------------------------------------
__global__ __launch_bounds__(256) void k_scanA(const int* __restrict__ cnt, int S,
                                               int* __restrict__ bsum){
  __shared__ int sh[256];
  int base = blockIdx.x * 1024 + threadIdx.x * 4;
  int s = 0;
  #pragma unroll
  for (int k = 0; k < 4; ++k){ int idx = base + k; if (idx < S) s += cnt[idx]; }
  sh[threadIdx.x] = s; __syncthreads();
  for (int off = 128; off > 0; off >>= 1){
    if (threadIdx.x < off) sh[threadIdx.x] += sh[threadIdx.x + off];
    __syncthreads();
  }
  if (threadIdx.x == 0) bsum[blockIdx.x] = sh[0];
}

__global__ __launch_bounds__(256) void k_scanC3(const int* __restrict__ cnt, int S,
    const int* __restrict__ bsum, int nb, int* __restrict__ offs){
  __shared__ int shb[256];
  __shared__ int sh[256];
  int t = threadIdx.x;
  int b = (int)blockIdx.x;
  shb[t] = (t < nb) ? bsum[t] : 0;
  __syncthreads();
  for (int off = 1; off < 256; off <<= 1){
    int v = (t >= off) ? shb[t - off] : 0; __syncthreads();
    shb[t] += v; __syncthreads();
  }
  int bbase = (b == 0) ? 0 : shb[b - 1];           // exclusive block prefix
  int base = b * 1024 + t * 4;
  int c[4]; int s = 0;
  #pragma unroll
  for (int k = 0; k < 4; ++k){ int idx = base + k; c[k] = (idx < S) ? cnt[idx] : 0; s += c[k]; }
  sh[t] = s; __syncthreads();
  for (int off = 1; off < 256; off <<= 1){
    int v = (t >= off) ? sh[t - off] : 0; __syncthreads();
    sh[t] += v; __syncthreads();
  }
  int run = bbase + sh[t] - s;                     // exclusive prefix for this thread
  #pragma unroll
  for (int k = 0; k < 4; ++k){
    int idx = base + k;
    if (idx < S){ offs[idx] = run; run += c[k]; }
  }
}

// ---------------------------------------------------------------------------
// pure-scatter placements (ranks precomputed; zero atomics)
// ---------------------------------------------------------------------------
__global__ __launch_bounds__(256) void k_place_e(
    const int* __restrict__ edges, const int* __restrict__ vertex, int NNZ,
    const int* __restrict__ offs, const int* __restrict__ rank_e,
    int* __restrict__ rows){
  int i = (int)blockIdx.x * 256 + (int)threadIdx.x;
  if (i < NNZ) rows[offs[edges[i]] + rank_e[i]] = vertex[i];
}

__global__ __launch_bounds__(256) void k_place_v(
    const int* __restrict__ edges, const int* __restrict__ vertex, int NNZ,
    const int* __restrict__ offsV, const int* __restrict__ rank_v,
    int* __restrict__ rowsV){
  int i = (int)blockIdx.x * 256 + (int)threadIdx.x;
  if (i < NNZ) rowsV[offsV[vertex[i]] + rank_v[i]] = edges[i];
}

// ---------------------------------------------------------------------------
// seg_body v4 (exact R4/R5/R9/R10-proven 2-deep version, on-the-fly logits —
// R12's precomputed weights regressed: extra dependent gather beat the saved
// VALU in this latency-bound loop).
// ---------------------------------------------------------------------------
template<int OUT_BF16>
__device__ __forceinline__ void seg_body(const uint4* __restrict__ feat,
    const float* __restrict__ att, const int* __restrict__ rows_sorted,
    const int* __restrict__ offs, const int* __restrict__ cnt,
    const int* __restrict__ stype, void* __restrict__ outbuf,
    int S, int blockId, int tid){
  int wid = tid >> 6, lane = tid & 63;
  int s = blockId * 4 + wid;
  if (s >= S) return;
  int t = stype[s];
  int sub = lane >> 4, lane16 = lane & 15;         // sub-wave row slot, lane-in-row
  const float4* ap = (const float4*)(att + t * 128 + lane16 * 8);
  float4 A0 = ap[0], A1 = ap[1];
  int start = offs[s], len = cnt[s];
  float denom = 0.f;
  float acc[8];
  #pragma unroll
  for (int e = 0; e < 8; ++e) acc[e] = 0.f;

  for (int base = 0; base < len; base += 64){
    int m = len - base; if (m > 64) m = 64;
    int idx = 0;                                   // lanes >= m: safe dummy (row 0)
    if (lane < m) idx = rows_sorted[start + base + lane];
    int ng = (m + 3) >> 2;                         // groups of 4 rows
    uint4 uA = make_uint4(0,0,0,0), uB = make_uint4(0,0,0,0);
    {
      int r0 = __shfl(idx, sub);                   // uniform flow
      if (sub < m) uA = feat[(size_t)r0 * 16 + lane16];
      int r1 = __shfl(idx, 4 + sub);               // uniform flow
      if (4 + sub < m) uB = feat[(size_t)r1 * 16 + lane16];
    }
    for (int g = 0; g < ng; g += 2){
      {
        uint4 u = uA;
        int nr = (g + 2) * 4 + sub;
        int rn = __shfl(idx, nr & 63);             // UNCONDITIONAL (uniform)
        if (nr < m) uA = feat[(size_t)rn * 16 + lane16];  // load-only guard
        float x0 = bflo(u.x), x1 = bfhi(u.x), x2 = bflo(u.y), x3 = bfhi(u.y);
        float x4 = bflo(u.z), x5 = bfhi(u.z), x6 = bflo(u.w), x7 = bfhi(u.w);
        float p = x0*A0.x + x1*A0.y + x2*A0.z + x3*A0.w
                + x4*A1.x + x5*A1.y + x6*A1.z + x7*A1.w;
        p += __shfl_xor(p, 1);                     // complete 16-chan head dot
        float wgt = __expf(lrelu(p));
        wgt = (g * 4 + sub < m) ? wgt : 0.f;       // mask pad rows (exp(0)=1!)
        denom += wgt;
        acc[0] += wgt*x0; acc[1] += wgt*x1; acc[2] += wgt*x2; acc[3] += wgt*x3;
        acc[4] += wgt*x4; acc[5] += wgt*x5; acc[6] += wgt*x6; acc[7] += wgt*x7;
      }
      if (g + 1 < ng){                             // ng uniform -> uniform branch
        uint4 u = uB;
        int nr = (g + 3) * 4 + sub;
        int rn = __shfl(idx, nr & 63);             // UNCONDITIONAL (uniform)
        if (nr < m) uB = feat[(size_t)rn * 16 + lane16];
        float x0 = bflo(u.x), x1 = bfhi(u.x), x2 = bflo(u.y), x3 = bfhi(u.y);
        float x4 = bflo(u.z), x5 = bfhi(u.z), x6 = bflo(u.w), x7 = bfhi(u.w);
        float p = x0*A0.x + x1*A0.y + x2*A0.z + x3*A0.w
                + x4*A1.x + x5*A1.y + x6*A1.z + x7*A1.w;
        p += __shfl_xor(p, 1);
        float wgt = __expf(lrelu(p));
        wgt = ((g + 1) * 4 + sub < m) ? wgt : 0.f;
        denom += wgt;
        acc[0] += wgt*x0; acc[1] += wgt*x1; acc[2] += wgt*x2; acc[3] += wgt*x3;
        acc[4] += wgt*x4; acc[5] += wgt*x5; acc[6] += wgt*x6; acc[7] += wgt*x7;
      }
    }
  }
  // cross-sub-wave reduction (same lane16 <-> same head)
  denom += __shfl_xor(denom, 16);
  denom += __shfl_xor(denom, 32);
  #pragma unroll
  for (int e = 0; e < 8; ++e){
    acc[e] += __shfl_xor(acc[e], 16);
    acc[e] += __shfl_xor(acc[e], 32);
  }
  float inv = 1.f / (denom + 1e-16f);
  float v[8];
  #pragma unroll
  for (int e = 0; e < 8; ++e) v[e] = acc[e] * inv;

  if constexpr (OUT_BF16){
    if (sub == 0){
      uint4 pw;
      pw.x = (unsigned)f2bf(fmaxf(v[0],0.f)) | ((unsigned)f2bf(fmaxf(v[1],0.f)) << 16);
      pw.y = (unsigned)f2bf(fmaxf(v[2],0.f)) | ((unsigned)f2bf(fmaxf(v[3],0.f)) << 16);
      pw.z = (unsigned)f2bf(fmaxf(v[4],0.f)) | ((unsigned)f2bf(fmaxf(v[5],0.f)) << 16);
      pw.w = (unsigned)f2bf(fmaxf(v[6],0.f)) | ((unsigned)f2bf(fmaxf(v[7],0.f)) << 16);
      ((uint4*)outbuf)[(size_t)s * 16 + lane16] = pw;
    }
  } else {
    if (sub == 0){
      float4* op = (float4*)outbuf;
      op[(size_t)s * 32 + lane16 * 2]     = make_float4(v[0], v[1], v[2], v[3]);
      op[(size_t)s * 32 + lane16 * 2 + 1] = make_float4(v[4], v[5], v[6], v[7]);
    }
  }
}

// ---------------------------------------------------------------------------
// K_B: [hist_v | seg1], period 5 (r0 hist_v, r1-4 seg1).  R6-measured: 56.3us.
// Disjoint memory: hist_v writes cnt[E..S)/rank_v; seg1 reads rows/offs/cnt[0,E).
// ---------------------------------------------------------------------------
__global__ __launch_bounds__(256) void k_seg1_histv(
    const int* __restrict__ vertex, int NNZ,
    int* __restrict__ cntV, int* __restrict__ rank_v, int nbHist,
    const uint4* __restrict__ X0, const float* __restrict__ att_e,
    const int* __restrict__ rows, const int* __restrict__ offs,
    const int* __restrict__ cnt, const int* __restrict__ etype,
    void* __restrict__ Xe, int E, int nbSeg){
  const int q = (int)blockIdx.x / 5, r = (int)blockIdx.x % 5;
  if (r == 0){
    if (q < nbHist){
      int i = q * 256 + (int)threadIdx.x;
      if (i < NNZ) rank_v[i] = atomicAdd(cntV + vertex[i], 1);
    }
    return;
  }
  int segBlk = q * 4 + (r - 1);
  if (segBlk >= nbSeg) return;
  seg_body<1>(X0, att_e, rows, offs, cnt, etype, Xe, E, segBlk, threadIdx.x);
}

__global__ __launch_bounds__(256) void k_seg2(const uint4* __restrict__ Xe,
    const float* __restrict__ att_v, const int* __restrict__ rows,
    const int* __restrict__ offs, const int* __restrict__ cnt,
    const int* __restrict__ vtype, float* __restrict__ out, int N){
  seg_body<0>(Xe, att_v, rows, offs, cnt, vtype, out, N,
              (int)blockIdx.x, threadIdx.x);
}

extern "C" void kernel_launch(void* const* d_in, const int* in_sizes, int n_in,
                              void* d_out, int out_size, void* d_ws, size_t ws_size,
                              hipStream_t stream){
  const float* X      = (const float*)d_in[0];
  const float* W      = (const float*)d_in[1];
  const float* att_e  = (const float*)d_in[2];
  const float* att_v  = (const float*)d_in[3];
  const int*   vertex = (const int*)d_in[4];
  const int*   edges  = (const int*)d_in[5];
  const int*   vtype  = (const int*)d_in[6];
  const int*   etype  = (const int*)d_in[7];
  float* out = (float*)d_out;
  const int N   = in_sizes[0] / 128;
  const int NNZ = in_sizes[4];
  const int E   = in_sizes[7];
  const int S   = E + N;

  const int nbI = (NNZ + 255) / 256;                  // hist/place blocks
  const int nbHN = (N + 255) / 256;                   // type-hist blocks
  const int nbSE = (E + 1023) / 1024;                 // edge-scan blocks
  const int nbSV = (N + 1023) / 1024;                 // vertex-scan blocks
  const int nbSeg1 = (E + 3) / 4;                     // seg1 blocks
  const int nbPad = (N + 252 + 63) / 64;              // padded gemm blocks
  const int nsortedCap = nbPad * 64;                  // FULL gemm-grid coverage
  const int nQA = (nbPad > (nbI + 1) / 2) ? nbPad : (nbI + 1) / 2;
  const int nQB = (nbI > (nbSeg1 + 3) / 4) ? nbI : (nbSeg1 + 3) / 4;

  // workspace carve (~52.9MB, identical to R10)
  char* wp = (char*)d_ws;
  int* cnt    = (int*)wp; wp += (size_t)S * 4;        // [0,E) edge, [E,S) vertex
  int* tcnt   = (int*)wp; wp += 16;                   // node-type counts
  int* tcur   = (int*)wp; wp += 16;                   // node-type cursors
  int* offs   = (int*)wp; wp += (size_t)S * 4;        // [0,E) abs; [E,S) rel to NNZ
  int* bsum   = (int*)wp; wp += 1024;                 // up to 256 block sums
  int* rows   = (int*)wp; wp += (size_t)2 * NNZ * 4;  // [0,NNZ) edge-grp, [NNZ,2NNZ) vtx-grp
  int* nsorted= (int*)wp; wp += (size_t)nsortedCap * 4; // type-sorted node ids (pad = -1)
  int* rank_e = (int*)wp; wp += (size_t)NNZ * 4;      // within-edge-key arrival rank
  int* rank_v = (int*)wp; wp += (size_t)NNZ * 4;      // within-vtx-key arrival rank
  unsigned short* X0 = (unsigned short*)wp; wp += (size_t)N * 128 * 2;
  unsigned short* Xe = (unsigned short*)wp; wp += (size_t)E * 128 * 2;
  short* Bfrag = (short*)wp; wp += (size_t)65536 * 2;

  hipMemsetAsync(cnt, 0, (size_t)(S + 8) * 4, stream);          // cnt + tcnt + tcur
  hipMemsetAsync(nsorted, 0xFF, (size_t)nsortedCap * 4, stream); // -1 sentinels

  // prep: type-hist + Bfrag pack; node placement (pbase inline from tcnt)
  k_prep<<<nbHN + 256, 256, 0, stream>>>(vtype, N, tcnt, nbHN, W, Bfrag);
  k_nodeplace<<<nbHN, 256, 0, stream>>>(vtype, N, tcnt, tcur, nsorted);

  // K_A: gemm overlapped with edge-side hist only (period 3)
  k_gemm_hist<<<3 * nQA, 256, 0, stream>>>(X, Bfrag, nsorted, tcnt,
      (unsigned short*)X0, edges, NNZ, cnt, rank_e, nbI);

  // edge-side scan (2 launches) + atomic-free placement
  k_scanA<<<nbSE, 256, 0, stream>>>(cnt, E, bsum);
  k_scanC3<<<nbSE, 256, 0, stream>>>(cnt, E, bsum, nbSE, offs);
  k_place_e<<<nbI, 256, 0, stream>>>(edges, vertex, NNZ, offs, rank_e, rows);

  // K_B: seg1 overlapped with vertex-side hist (period 5, R6-measured 56.3us)
  k_seg1_histv<<<5 * nQB, 256, 0, stream>>>(vertex, NNZ, cnt + E, rank_v, nbI,
      (const uint4*)X0, att_e, rows, offs, cnt, etype, Xe, E, nbSeg1);

  // vertex-side scan + atomic-free placement (offsets relative to rows+NNZ)
  k_scanA<<<nbSV, 256, 0, stream>>>(cnt + E, N, bsum);
  k_scanC3<<<nbSV, 256, 0, stream>>>(cnt + E, N, bsum, nbSV, offs + E);
  k_place_v<<<nbI, 256, 0, stream>>>(edges, vertex, NNZ, offs + E, rank_v,
      rows + NNZ);

  k_seg2<<<(N + 3) / 4, 256, 0, stream>>>((const uint4*)Xe, att_v,
      rows + NNZ, offs + E, cnt + E, vtype, out, N);
}